// Round 12
// baseline (130.993 us; speedup 1.0000x reference)
//
#include <hip/hip_runtime.h>

// R11: scalar-stream gather. R10 post-mortem: ds_read+shfl in every feat
// address chain + working set > 4MB/XCD L2 -> 48us wall across 3 structures.
// Fix: entries are wave-uniform -> R4-verified closed-form fill writes a
// bin-sorted entries array; gather waves walk contiguous slices with batched
// UNIFORM loads (SMEM path), 6 independent feat loads in flight, no LDS/shfl
// in the chain, scalar run-merge. XCD banding via blockIdx swizzle so each
// XCD's feat rows fit its private L2. Segment start = constexpr prefix.

constexpr int D = 40, H = 32, W = 88, HW = H * W;       // 2816
constexpr int C = 128, NCAM = 6;
constexpr int BEV = 125, NBINS = BEV * BEV;             // 15625
constexpr int NPTS = D * HW;                            // 112640
constexpr int NCOLS = NCAM * HW;                        // 16896

typedef __attribute__((ext_vector_type(8))) unsigned short us8;
typedef __attribute__((ext_vector_type(4))) float f4;

__device__ __forceinline__ unsigned short f2bf(float x) {   // RNE
    unsigned u = __float_as_uint(x);
    return (unsigned short)((u + 0x7FFF + ((u >> 16) & 1)) >> 16);
}
__device__ __forceinline__ float b2f(unsigned short u) {
    return __uint_as_float(((unsigned)u) << 16);
}

__device__ __forceinline__ int ix_of(int w, float dep) {
    float gx = __fadd_rn(__fmul_rn(__fdiv_rn((float)w * dep, 3567.0f), 100.0f), -50.0f);
    return (int)__fdiv_rn(__fadd_rn(gx, 50.0f), 0.8f);
}
__device__ __forceinline__ int iy_of(int h, float dep) {
    float gy = __fadd_rn(__fmul_rn(__fdiv_rn((float)h * dep, 1271.0f), 100.0f), -50.0f);
    return (int)__fdiv_rn(__fadd_rn(gy, 50.0f), 0.8f);
}

// ---------------------------------------------------------------- constexpr tables
struct Tabs { short XP[D][126]; short YP[D][126]; };
constexpr Tabs make_tabs() {
    Tabs t{};
    for (int d = 0; d < D; ++d) {
        int dep = d + 2;
        int cntx[126] = {};
        for (int w = 0; w < W; ++w) {
            float gx = (float)(w * dep) / 3567.0f * 100.0f - 50.0f;
            int ix = (int)((gx + 50.0f) / 0.8f);
            if (ix < 125) cntx[ix]++;
        }
        t.XP[d][0] = 0;
        for (int X = 0; X < 125; ++X) t.XP[d][X + 1] = (short)(t.XP[d][X] + cntx[X]);
        int cnty[126] = {};
        for (int h = 0; h < H; ++h) {
            float gy = (float)(h * dep) / 1271.0f * 100.0f - 50.0f;
            int iy = (int)((gy + 50.0f) / 0.8f);
            if (iy < 125) cnty[iy]++;
        }
        t.YP[d][0] = 0;
        for (int Y = 0; Y < 125; ++Y) t.YP[d][Y + 1] = (short)(t.YP[d][Y] + cnty[Y]);
    }
    return t;
}
__device__ const Tabs g_tab = make_tabs();

// ---------------------------------------------------------------- constexpr segments
// Emission order (row, X, d) == entries order (bin, d) -> start is a running
// prefix. a: iy<<16|X0<<8|X1 ; b: split<<31|count ; start: entry offset.
struct SegTable { unsigned a[4096]; unsigned b[4096]; unsigned start[4096]; int n; };

constexpr SegTable make_segs() {
    SegTable S{};
    Tabs t = make_tabs();
    int ns = 0;
    unsigned running = 0;
    for (int iy = 0; iy < 125; ++iy) {
        int cnt[125] = {};
        for (int d = 0; d < D; ++d) {
            int yc = t.YP[d][iy + 1] - t.YP[d][iy];
            if (yc == 0) continue;
            for (int X = 0; X < 125; ++X)
                cnt[X] += (t.XP[d][X + 1] - t.XP[d][X]) * yc;
        }
        int X = 0;
        while (X < 125) {
            if (cnt[X] > 176) {                      // heavy bin: d-split
                int d0 = 0;
                while (d0 < D) {
                    int run = 0, d1 = d0;
                    while (d1 < D) {
                        int piece = (t.XP[d1][X + 1] - t.XP[d1][X]) *
                                    (t.YP[d1][iy + 1] - t.YP[d1][iy]);
                        if (d1 > d0 && run + piece > 128) break;
                        run += piece; ++d1;
                    }
                    if (run > 0) {
                        S.a[ns] = ((unsigned)iy << 16) | ((unsigned)X << 8) | (unsigned)(X + 1);
                        S.b[ns] = (1u << 31) | (unsigned)run;
                        S.start[ns] = running; running += (unsigned)run;
                        ++ns;
                    }
                    d0 = d1;
                }
                ++X;
            } else {
                int X0 = X, run = 0;
                while (X < 125 && (X - X0) < 16 && cnt[X] <= 176 &&
                       (X == X0 || run + cnt[X] <= 128)) {
                    run += cnt[X]; ++X;
                }
                if (run > 0) {
                    S.a[ns] = ((unsigned)iy << 16) | ((unsigned)X0 << 8) | (unsigned)X;
                    S.b[ns] = (unsigned)run;
                    S.start[ns] = running; running += (unsigned)run;
                    ++ns;
                }
            }
        }
    }
    S.n = ns;
    return S;
}
constexpr SegTable g_ct = make_segs();
constexpr int NSEG = g_ct.n;
static_assert(NSEG > 0 && NSEG <= 4096, "seg table overflow");
__device__ const SegTable g_segs = g_ct;

// ---------------------------------------------------------------- D1: mega
// pack | softmax | zero-out | fill (R4-verified closed-form bin-sorted fill)
constexpr int PACK_BLOCKS = (C / 8) * (HW / 32);   // 1408
constexpr int SMAX_BLOCKS = NCOLS / 256;           // 66
constexpr int ZERO_TOTAL  = C * NBINS / 4;         // 500000 f4
constexpr int ZERO_BLOCKS = (ZERO_TOTAL + 1023) / 1024;  // 489
constexpr int FILL_BLOCKS = NPTS / 256;            // 440
constexpr int MEGA_BLOCKS = PACK_BLOCKS + SMAX_BLOCKS + ZERO_BLOCKS + FILL_BLOCKS;

__global__ void __launch_bounds__(256) mega_kernel(
        const float* __restrict__ feat,     // [NCAM][C][HW]
        const float* __restrict__ logits,   // [NCAM][D][HW]
        float* __restrict__ probs_t,
        unsigned short* __restrict__ feat_p,
        unsigned* __restrict__ entries,
        float* __restrict__ out) {
    __shared__ __align__(16) float tile[NCAM * 8 * 37];
    int b = blockIdx.x, t = threadIdx.x;

    if (b < PACK_BLOCKS) {
        int c0  = (b / 88) * 8;
        int hw0 = (b % 88) * 32;
        int cq = t >> 5, hwL = t & 31;
#pragma unroll
        for (int n = 0; n < NCAM; ++n)
            tile[(n * 8 + cq) * 37 + hwL] =
                feat[((size_t)(n * C + c0 + cq)) * HW + hw0 + hwL];
        __syncthreads();
        int hl = t >> 3, cL = t & 7;
        us8 v;
#pragma unroll
        for (int n = 0; n < NCAM; ++n)
            v[n] = f2bf(tile[(n * 8 + cL) * 37 + hl]);
        v[6] = 0; v[7] = 0;
        *(us8*)(feat_p + ((size_t)(hw0 + hl) * C + (c0 + cL)) * 8) = v;

    } else if (b < PACK_BLOCKS + SMAX_BLOCKS) {
        int col = (b - PACK_BLOCKS) * 256 + t;       // < NCOLS exact
        int n  = col / HW;
        int hw = col - n * HW;
        const float* src = logits + ((size_t)n * D) * HW + hw;
        float v[D];
        float m = -3.402823466e+38f;
#pragma unroll
        for (int d = 0; d < D; ++d) {
            v[d] = src[(size_t)d * HW];
            m = fmaxf(m, v[d]);
        }
        float s = 0.f;
#pragma unroll
        for (int d = 0; d < D; ++d) { v[d] = expf(v[d] - m); s += v[d]; }
        float inv = 1.0f / s;
#pragma unroll
        for (int d = 0; d < D; ++d)
            probs_t[(size_t)((d << 12) | hw) * 8 + n] = v[d] * inv;

    } else if (b < PACK_BLOCKS + SMAX_BLOCKS + ZERO_BLOCKS) {
        int base = (b - PACK_BLOCKS - SMAX_BLOCKS) * 1024;
#pragma unroll
        for (int k = 0; k < 4; ++k) {
            int i = base + k * 256 + t;
            if (i < ZERO_TOTAL) ((f4*)out)[i] = f4{0.f, 0.f, 0.f, 0.f};
        }

    } else {
        int pt = (b - PACK_BLOCKS - SMAX_BLOCKS - ZERO_BLOCKS) * 256 + t; // < NPTS
        int d = pt / HW, hw = pt - d * HW, h = hw / W, w = hw - h * W;
        float dep = (float)(d + 2);
        int X = ix_of(w, dep), Y = iy_of(h, dep);
        if (X <= 124 && Y <= 124) {
            int pos = 0;
#pragma unroll 8
            for (int dd = 0; dd < D; ++dd) {          // entries before (bin,d)
                int ypY = g_tab.YP[dd][Y];
                int yc  = g_tab.YP[dd][Y + 1] - ypY;
                int xpX = g_tab.XP[dd][X];
                int xc  = g_tab.XP[dd][X + 1] - xpX;
                pos += ypY * g_tab.XP[dd][125] + yc * xpX
                     + ((dd < d) ? xc * yc : 0);
            }
            pos += (h - g_tab.YP[d][Y]) * (g_tab.XP[d][X + 1] - g_tab.XP[d][X])
                 + (w - g_tab.XP[d][X]);
            unsigned bin = (unsigned)(Y * BEV + X);
            entries[pos] = (bin << 18) | ((unsigned)d << 12) | (unsigned)hw;
        }
    }
}

// ---------------------------------------------------------------- D2: gather
// Grid = NSEG*2 (XCD-banded). 128 thr = 2 waves; lane = channel within chalf.
// Wave dg consumes contiguous half [beg,end) of the segment's entries slice:
// batched UNIFORM entry loads (6 at a time) -> 6 independent feat loads in
// flight -> scalar run-merge on wave-uniform bl -> per-wave LDS tile ->
// exactly-once coalesced flush (atomicAdd only for d-split segments).
constexpr int GTOT = NSEG * 2;

__global__ void __launch_bounds__(128, 4) gather_kernel(
        const unsigned short* __restrict__ feat_p,   // [hw][c][8] bf16
        const float* __restrict__ probs_t,           // [(d<<12)|hw][8] f32
        const unsigned* __restrict__ entries,
        float* __restrict__ out) {                   // [C][NBINS]
    __shared__ float T[2][16][66];                   // 8.25 KB
    // XCD banding: blocks with same (blockIdx%8) get a contiguous index band.
    int u = (int)(blockIdx.x & 7) * ((GTOT + 7) / 8) + (int)(blockIdx.x >> 3);
    if (u >= GTOT) return;
    int slot = u >> 1, chalf = u & 1;
    unsigned da = g_segs.a[slot], db = g_segs.b[slot];
    unsigned s0 = g_segs.start[slot];
    int iy = da >> 16, X0 = (da >> 8) & 0xFF, X1 = da & 0xFF;
    int width = X1 - X0;
    bool split = (db >> 31) != 0;
    int P = (int)(db & 0x7FFFFFFF);
    int binbase = iy * BEV + X0;
    int t = threadIdx.x;
    int lane = t & 63, dg = t >> 6;
    float* Tp = &T[dg][0][0];

    for (int i = lane; i < 16 * 66; i += 64) Tp[i] = 0.f;   // own tile

    int half = (P + 1) >> 1;
    int beg = (int)s0 + (dg ? half : 0);
    int end = (int)s0 + (dg ? P : half);

    float racc = 0.f;
    int rbl = -1;
    int i = beg;
    for (; i + 6 <= end; i += 6) {
        unsigned pk[6];
#pragma unroll
        for (int j = 0; j < 6; ++j) pk[j] = entries[i + j];   // uniform loads
        us8 fv[6];
#pragma unroll
        for (int j = 0; j < 6; ++j)                           // 6 indep loads
            fv[j] = *(const us8*)(feat_p +
                     (((size_t)(pk[j] & 0xFFFu) * C + (unsigned)(chalf * 64 + lane)) * 8));
#pragma unroll
        for (int j = 0; j < 6; ++j) {
            const float* pp = probs_t + ((size_t)(pk[j] & 0x3FFFFu) << 3);
            float s = ((pp[0] * b2f(fv[j][0]) + pp[1] * b2f(fv[j][1]))
                     + (pp[2] * b2f(fv[j][2]) + pp[3] * b2f(fv[j][3])))
                     + (pp[4] * b2f(fv[j][4]) + pp[5] * b2f(fv[j][5]));
            int bl = (int)(pk[j] >> 18) - binbase;            // wave-uniform
            if (bl != rbl) {
                if (rbl >= 0) Tp[rbl * 66 + lane] += racc;
                rbl = bl; racc = s;
            } else racc += s;
        }
    }
    for (; i < end; ++i) {                                    // tail
        unsigned pk = entries[i];
        us8 fv = *(const us8*)(feat_p +
                  (((size_t)(pk & 0xFFFu) * C + (unsigned)(chalf * 64 + lane)) * 8));
        const float* pp = probs_t + ((size_t)(pk & 0x3FFFFu) << 3);
        float s = ((pp[0] * b2f(fv[0]) + pp[1] * b2f(fv[1]))
                 + (pp[2] * b2f(fv[2]) + pp[3] * b2f(fv[3])))
                 + (pp[4] * b2f(fv[4]) + pp[5] * b2f(fv[5]));
        int bl = (int)(pk >> 18) - binbase;
        if (bl != rbl) {
            if (rbl >= 0) Tp[rbl * 66 + lane] += racc;
            rbl = bl; racc = s;
        } else racc += s;
    }
    if (rbl >= 0) Tp[rbl * 66 + lane] += racc;
    __syncthreads();

#pragma unroll
    for (int it = 0; it < 8; ++it) {                 // 16 bl x 8 cc per iter
        int bl = t & 15, cc = it * 8 + (t >> 4);     // cc in [0,64)
        if (bl < width) {
            float v = T[0][bl][cc] + T[1][bl][cc];
            float* dst = &out[(size_t)(chalf * 64 + cc) * NBINS + binbase + bl];
            if (split) atomicAdd(dst, v);
            else       *dst = v;
        }
    }
}

// ---------------------------------------------------------------- launch
extern "C" void kernel_launch(void* const* d_in, const int* in_sizes, int n_in,
                              void* d_out, int out_size, void* d_ws, size_t ws_size,
                              hipStream_t stream) {
    const float* img_feat     = (const float*)d_in[0];
    const float* depth_logits = (const float*)d_in[1];
    float* out = (float*)d_out;

    char* p = (char*)d_ws;
    float*          probs_t = (float*)p;          p += (size_t)D * 4096 * 8 * 4;  // 5.24 MB
    unsigned short* feat_p  = (unsigned short*)p; p += (size_t)HW * C * 8 * 2;    // 5.77 MB
    unsigned*       entries = (unsigned*)p;       p += (size_t)NPTS * 4;          // 450 KB

    mega_kernel<<<MEGA_BLOCKS, 256, 0, stream>>>(
        img_feat, depth_logits, probs_t, feat_p, entries, out);
    gather_kernel<<<((GTOT + 7) / 8) * 8, 128, 0, stream>>>(feat_p, probs_t, entries, out);
}